// Round 13
// baseline (392.798 us; speedup 1.0000x reference)
//
#include <hip/hip_runtime.h>
#include <math.h>

#define SRATE   48000
#define NFFT    2048
#define N1      1024          // half-size complex FFT per real frame
#define HOP     64
#define NMELS   128
#define NFREQ   1025          // NFFT/2 + 1
#define NTGT    64
#define BATCH   32
#define NFRAMES 751           // 1 + 48000/64
#define MELSZ   (NMELS * NFRAMES)   // 96128 = 751*128
#define NCHUNK  751
#define PADW    132           // padded LDS row stride (floats) in diff kernel
#define NTILE   376           // ceil(751/2): 2 frames per melspec block

// float2-element pad: bank-pair coverage <=4/wave64 (HW minimum for b64)
// for all phase read/write patterns (stride-64 reads, 16l+r / 256j+k+16r /
// t+256r writes) — hand-verified per pattern.
__device__ __forceinline__ int P2(int a) { return a + (a >> 4); }
#define ZBUF 1087             // P2(1023)+1

__device__ __forceinline__ float2 cmul(float2 a, float2 b) {
  return make_float2(a.x * b.x - a.y * b.y, a.x * b.y + a.y * b.x);
}

// DFT4 with W4 = -i convention (verified in rounds 10-12, absmax 0.0):
// X0=u0+u1+u2+u3; X1=d0-i*d1; X2=s0-s1; X3=d0+i*d1
__device__ __forceinline__ void dft4(float2& x0, float2& x1, float2& x2, float2& x3) {
  float s0r = x0.x + x2.x, s0i = x0.y + x2.y;
  float d0r = x0.x - x2.x, d0i = x0.y - x2.y;
  float s1r = x1.x + x3.x, s1i = x1.y + x3.y;
  float d1r = x1.x - x3.x, d1i = x1.y - x3.y;
  x0 = make_float2(s0r + s1r, s0i + s1i);
  x1 = make_float2(d0r + d1i, d0i - d1r);
  x2 = make_float2(s0r - s1r, s0i - s1i);
  x3 = make_float2(d0r - d1i, d0i + d1r);
}

#define W16_1 make_float2(0.92387953251128674f, -0.38268343236508978f)
#define W16_2 make_float2(0.70710678118654752f, -0.70710678118654752f)
#define W16_3 make_float2(0.38268343236508978f, -0.92387953251128674f)
#define W16_4 make_float2(0.0f, -1.0f)
#define W16_6 make_float2(-0.70710678118654752f, -0.70710678118654752f)
#define W16_9 make_float2(-0.92387953251128674f, 0.38268343236508978f)

// 16-point DFT in registers = 2 fused radix-4 levels.
// In: a[m]. Out: X[s+4q] located at a[q+4s] (4x4 index transpose).
__device__ __forceinline__ void r16(float2 (&a)[16]) {
  dft4(a[0], a[4], a[8],  a[12]);
  dft4(a[1], a[5], a[9],  a[13]);
  dft4(a[2], a[6], a[10], a[14]);
  dft4(a[3], a[7], a[11], a[15]);
  // a[m1+4s] = b[m1][s]; twiddle by W16^{s*m1}
  a[5]  = cmul(a[5],  W16_1);
  a[6]  = cmul(a[6],  W16_2);
  a[7]  = cmul(a[7],  W16_3);
  a[9]  = cmul(a[9],  W16_2);
  a[10] = cmul(a[10], W16_4);
  a[11] = cmul(a[11], W16_6);
  a[13] = cmul(a[13], W16_3);
  a[14] = cmul(a[14], W16_6);
  a[15] = cmul(a[15], W16_9);
  dft4(a[0],  a[1],  a[2],  a[3]);
  dft4(a[4],  a[5],  a[6],  a[7]);
  dft4(a[8],  a[9],  a[10], a[11]);
  dft4(a[12], a[13], a[14], a[15]);
}

// ---------------------------------------------------------------------------
// Setup: Hann window float2 pairs + full twiddle table W_2048^k, k<2048.
// ---------------------------------------------------------------------------
__global__ __launch_bounds__(256) void tab_kernel(
    float2* __restrict__ wtab2, float2* __restrict__ gtw) {
  int i = blockIdx.x * 256 + threadIdx.x;
  if (i < N1) {
    float w0 = 0.5f - 0.5f * cosf((float)(2.0 * M_PI / NFFT) * (float)(2 * i));
    float w1 = 0.5f - 0.5f * cosf((float)(2.0 * M_PI / NFFT) * (float)(2 * i + 1));
    wtab2[i] = make_float2(w0, w1);
  }
  {
    float sv, cv;
    sincosf(-(float)(2.0 * M_PI / NFFT) * (float)i, &sv, &cv);
    gtw[i] = make_float2(cv, sv);
  }
}

// ---------------------------------------------------------------------------
// Kernel T: transpose fb -> fbT and exact nonzero f-range per mel filter.
// ---------------------------------------------------------------------------
__global__ __launch_bounds__(256) void fbt_kernel(
    const float* __restrict__ fb, float* __restrict__ fbT,
    int* __restrict__ fs, int* __restrict__ fe) {
  int m = blockIdx.x;
  int tid = threadIdx.x;
  __shared__ int smin[256], smax[256];
  int lmin = NFREQ, lmax = -1;
  for (int f = tid; f < NFREQ; f += 256) {
    float v = fb[f * NMELS + m];
    fbT[m * NFREQ + f] = v;
    if (v > 0.0f) {
      if (f < lmin) lmin = f;
      if (f > lmax) lmax = f;
    }
  }
  smin[tid] = lmin;
  smax[tid] = lmax;
  __syncthreads();
  for (int off = 128; off > 0; off >>= 1) {
    if (tid < off) {
      smin[tid] = min(smin[tid], smin[tid + off]);
      smax[tid] = max(smax[tid], smax[tid + off]);
    }
    __syncthreads();
  }
  if (tid == 0) {
    fs[m] = smin[0];
    fe[m] = smax[0];
  }
}

// ---------------------------------------------------------------------------
// Kernel X: transpose targets [k][m][t] -> [k][t][m] (tiled, coalesced).
// ---------------------------------------------------------------------------
__global__ __launch_bounds__(256) void tpose_kernel(
    const float* __restrict__ tgt, float* __restrict__ tgtT) {
  __shared__ float tile[32][33];
  int k = blockIdx.z;
  int mt = blockIdx.y;            // 4 m-tiles
  int tt = blockIdx.x;            // 24 t-tiles
  int tx = threadIdx.x & 31, ty = threadIdx.x >> 5;   // 32 x 8
  const float* src = tgt + (size_t)k * MELSZ;
  float* dst = tgtT + (size_t)k * MELSZ;
  #pragma unroll
  for (int r = 0; r < 4; ++r) {
    int m = mt * 32 + ty + r * 8;
    int t = tt * 32 + tx;
    if (t < NFRAMES) tile[ty + r * 8][tx] = src[m * NFRAMES + t];
  }
  __syncthreads();
  #pragma unroll
  for (int r = 0; r < 4; ++r) {
    int t = tt * 32 + ty + r * 8;
    int m = mt * 32 + tx;
    if (t < NFRAMES) dst[t * 128 + m] = tile[tx][ty + r * 8];
  }
}

// ---------------------------------------------------------------------------
// Kernel A: 128 threads = 2 waves = 2 frames. Per frame: one wave does the
// 1024-pt FFT as radix 16*16*4 with 16 complex values per lane in registers;
// only 3 LDS exchanges (last radix-4 in-place). Unpack to powers, sparse mel,
// coalesced [b][t][m] write.
// ---------------------------------------------------------------------------
__global__ __launch_bounds__(128) void melspec_kernel(
    const float* __restrict__ x, const float* __restrict__ fbT,
    const int* __restrict__ fs, const int* __restrict__ fe,
    const float2* __restrict__ wtab2, const float2* __restrict__ gtw,
    float* __restrict__ mel) {
  __shared__ float2 z[2][2][ZBUF];   // 34784 B -> 4 blocks/CU

  int tid = threadIdx.x;
  int bi = blockIdx.x;
  int b = bi / NTILE;
  int tile = bi - b * NTILE;
  int wv = tid >> 6, l = tid & 63;
  int t = tile * 2 + wv;
  int tc = t < NFRAMES ? t : NFRAMES - 1;   // clamp: redundant compute, no write
  const float* xb = x + (size_t)b * SRATE;
  float2* A  = z[wv][0];
  float2* Bb = z[wv][1];

  // ---- load: z[n] = xw[2n] + i*xw[2n+1], reflect-pad + Hann ----
  int base = tc * HOP - NFFT / 2;
  #pragma unroll
  for (int m = 0; m < 16; ++m) {
    int n = l + (m << 6);
    int p0 = base + 2 * n;
    float2 v;
    if (p0 >= 0 && p0 + 1 < SRATE) {
      v = *(const float2*)(xb + p0);
    } else {
      int q0 = p0 < 0 ? -p0 : (p0 >= SRATE ? 2 * SRATE - 2 - p0 : p0);
      int p1 = p0 + 1;
      int q1 = p1 < 0 ? -p1 : (p1 >= SRATE ? 2 * SRATE - 2 - p1 : p1);
      v = make_float2(xb[q0], xb[q1]);
    }
    float2 w2 = wtab2[n];
    A[P2(n)] = make_float2(v.x * w2.x, v.y * w2.y);
  }
  __syncthreads();

  float2 a[16];

  // ---- phase 1: radix-16, L=1 (no outer twiddle). A -> B ----
  #pragma unroll
  for (int m = 0; m < 16; ++m) a[m] = A[P2(l + (m << 6))];
  r16(a);
  #pragma unroll
  for (int s = 0; s < 4; ++s)
    #pragma unroll
    for (int q = 0; q < 4; ++q)
      Bb[P2(16 * l + s + 4 * q)] = a[q + 4 * s];
  __syncthreads();

  // ---- phase 2: radix-16, L=16, outer twiddle W256^{k*m}=gtw[8km]. B -> A --
  {
    int k2 = l & 15, j2 = l >> 4;
    #pragma unroll
    for (int m = 0; m < 16; ++m) a[m] = Bb[P2(l + (m << 6))];
    #pragma unroll
    for (int m = 1; m < 16; ++m) a[m] = cmul(a[m], gtw[8 * k2 * m]);
    r16(a);
    int wb = j2 * 256 + k2;
    #pragma unroll
    for (int s = 0; s < 4; ++s)
      #pragma unroll
      for (int q = 0; q < 4; ++q)
        A[P2(wb + 16 * (s + 4 * q))] = a[q + 4 * s];
  }
  __syncthreads();

  // ---- phase 3: radix-4, L=256, twiddle W1024^{t*m}=gtw[2tm]. A in-place --
  #pragma unroll
  for (int g = 0; g < 4; ++g) {
    int t3 = l + (g << 6);   // < 256; per-lane slots disjoint -> in-place OK
    float2 u0 = A[P2(t3)],       u1 = A[P2(t3 + 256)];
    float2 u2 = A[P2(t3 + 512)], u3 = A[P2(t3 + 768)];
    u1 = cmul(u1, gtw[2 * t3]);
    u2 = cmul(u2, gtw[4 * t3]);
    u3 = cmul(u3, gtw[6 * t3]);
    dft4(u0, u1, u2, u3);
    A[P2(t3)] = u0;       A[P2(t3 + 256)] = u1;
    A[P2(t3 + 512)] = u2; A[P2(t3 + 768)] = u3;
  }
  __syncthreads();

  // ---- rfft unpack -> powers (plain floats into B) ----
  float* pw = (float*)Bb;
  for (int k = l; k <= 1024; k += 64) {
    int ka = P2(k & (N1 - 1)), kb = P2((N1 - k) & (N1 - 1));
    float2 Za = A[ka], Zb = A[kb];
    float Xer  = 0.5f * (Za.x + Zb.x), Xei = 0.5f * (Za.y - Zb.y);
    float Xor_ = 0.5f * (Za.y + Zb.y), Xoi = 0.5f * (Zb.x - Za.x);
    float2 w = gtw[k];
    float Xr = Xer + w.x * Xor_ - w.y * Xoi;
    float Xi = Xei + w.x * Xoi + w.y * Xor_;
    pw[k] = Xr * Xr + Xi * Xi;
  }
  __syncthreads();

  // ---- sparse mel projection; coalesced [b][t][m] writes ----
  int m = tid;                       // 0..127 = filter id
  int f0 = fs[m], f1 = fe[m];
  const float* col = fbT + (size_t)m * NFREQ;
  #pragma unroll
  for (int p = 0; p < 2; ++p) {
    int tt = tile * 2 + p;
    if (tt < NFRAMES) {
      const float* pwf = (const float*)z[p][1];
      float acc = 0.0f;
      for (int f = f0; f <= f1; ++f) acc += pwf[f] * col[f];
      mel[(size_t)b * MELSZ + (size_t)tt * 128 + m] = acc;
    }
  }
}

// ---------------------------------------------------------------------------
// Kernel B: L1 partials; chunk c = frame t (128 contiguous floats in both
// mel [b][t][m] and tgtT [k][t][m]); atomicAdd into diffs[2048].
// ---------------------------------------------------------------------------
__global__ __launch_bounds__(256) void diff_kernel(
    const float* __restrict__ mel, const float* __restrict__ tgtT,
    float* __restrict__ diffs) {
  __shared__ float mel_s[BATCH * PADW];
  __shared__ float tgt_s[NTGT * PADW];
  int tid = threadIdx.x;
  int bg = tid >> 4;        // 0..15 -> b in {2bg, 2bg+1}
  int kg = tid & 15;        // 0..15 -> k in {kg + 16i}, i<4
  int c = blockIdx.x;

  for (int q = tid; q < BATCH * 32; q += 256) {
    int row = q >> 5, c4 = q & 31;
    float4 v = *(const float4*)(mel + (size_t)row * MELSZ + c * 128 + c4 * 4);
    *(float4*)(&mel_s[row * PADW + c4 * 4]) = v;
  }
  for (int q = tid; q < NTGT * 32; q += 256) {
    int row = q >> 5, c4 = q & 31;
    float4 v = *(const float4*)(tgtT + (size_t)row * MELSZ + c * 128 + c4 * 4);
    *(float4*)(&tgt_s[row * PADW + c4 * 4]) = v;
  }
  __syncthreads();

  float acc[2][4];
  #pragma unroll
  for (int bi = 0; bi < 2; ++bi)
    #pragma unroll
    for (int i = 0; i < 4; ++i) acc[bi][i] = 0.0f;

  for (int j4 = 0; j4 < 32; ++j4) {
    float4 m0 = *(const float4*)(&mel_s[(2 * bg) * PADW + j4 * 4]);
    float4 m1 = *(const float4*)(&mel_s[(2 * bg + 1) * PADW + j4 * 4]);
    #pragma unroll
    for (int i = 0; i < 4; ++i) {
      int k = kg + (i << 4);
      float4 tv = *(const float4*)(&tgt_s[k * PADW + j4 * 4]);
      acc[0][i] += fabsf(m0.x - tv.x) + fabsf(m0.y - tv.y) +
                   fabsf(m0.z - tv.z) + fabsf(m0.w - tv.w);
      acc[1][i] += fabsf(m1.x - tv.x) + fabsf(m1.y - tv.y) +
                   fabsf(m1.z - tv.z) + fabsf(m1.w - tv.w);
    }
  }

  #pragma unroll
  for (int bi = 0; bi < 2; ++bi)
    #pragma unroll
    for (int i = 0; i < 4; ++i)
      atomicAdd(&diffs[(2 * bg + bi) * 64 + kg + (i << 4)], acc[bi][i]);
}

// ---------------------------------------------------------------------------
// Kernel C: scale by 1/MELSZ, min over 64 targets per batch row.
// ---------------------------------------------------------------------------
__global__ __launch_bounds__(256) void reduce_kernel(
    const float* __restrict__ diffs, float* __restrict__ out) {
  __shared__ float ds[256];
  int tid = threadIdx.x;
  int p = blockIdx.x * 256 + tid;
  ds[tid] = diffs[p] * (1.0f / (float)MELSZ);
  __syncthreads();
  if (tid < 4) {
    float mn = ds[tid * 64];
    #pragma unroll
    for (int kk = 1; kk < 64; ++kk) mn = fminf(mn, ds[tid * 64 + kk]);
    out[blockIdx.x * 4 + tid] = mn;
  }
}

// ---------------------------------------------------------------------------
extern "C" void kernel_launch(void* const* d_in, const int* in_sizes, int n_in,
                              void* d_out, int out_size, void* d_ws, size_t ws_size,
                              hipStream_t stream) {
  const float* x   = (const float*)d_in[0];   // (32, 48000)
  const float* tgt = (const float*)d_in[1];   // (64, 128, 751)
  const float* fb  = (const float*)d_in[2];   // (1025, 128)
  float* out = (float*)d_out;                 // (32,)

  char* ws = (char*)d_ws;
  size_t off = 0;
  float* fbT = (float*)(ws + off);
  off += ((size_t)NMELS * NFREQ * sizeof(float) + 255) & ~(size_t)255;
  int* fs = (int*)(ws + off); off += 1024;
  int* fe = (int*)(ws + off); off += 1024;
  float2* wtab2 = (float2*)(ws + off); off += N1 * sizeof(float2);
  float2* gtw   = (float2*)(ws + off); off += 2048 * sizeof(float2);
  float* mel = (float*)(ws + off);
  off += (size_t)BATCH * MELSZ * sizeof(float);
  float* tgtT = (float*)(ws + off);
  off += (size_t)NTGT * MELSZ * sizeof(float);
  float* diffs = (float*)(ws + off); off += 2048 * sizeof(float);

  hipMemsetAsync(diffs, 0, 2048 * sizeof(float), stream);
  tab_kernel<<<8, 256, 0, stream>>>(wtab2, gtw);
  fbt_kernel<<<NMELS, 256, 0, stream>>>(fb, fbT, fs, fe);
  tpose_kernel<<<dim3(24, 4, NTGT), 256, 0, stream>>>(tgt, tgtT);
  melspec_kernel<<<BATCH * NTILE, 128, 0, stream>>>(
      x, fbT, fs, fe, wtab2, gtw, mel);
  diff_kernel<<<NCHUNK, 256, 0, stream>>>(mel, tgtT, diffs);
  reduce_kernel<<<8, 256, 0, stream>>>(diffs, out);
}

// Round 14
// 246.379 us; speedup vs baseline: 1.5943x; 1.5943x over previous
//
#include <hip/hip_runtime.h>
#include <math.h>

#define SRATE   48000
#define NFFT    2048
#define N1      1024          // half-size complex FFT per real frame
#define HOP     64
#define NMELS   128
#define NFREQ   1025          // NFFT/2 + 1
#define NTGT    64
#define BATCH   32
#define NFRAMES 751           // 1 + 48000/64
#define MELSZ   (NMELS * NFRAMES)   // 96128 = 751*128
#define NCHUNK  751
#define PADW    132           // padded LDS row stride (floats) in diff kernel

// Padded LDS index (verified: absmax 0.0 in rounds 10-12).
__device__ __forceinline__ int SP(int a) { return a + 5 * (a >> 5); }
#define SBUF1 1179            // SP(1023)+1
__device__ __forceinline__ int TP(int a) { return a + (a >> 5); }
#define TWP   263             // TP(255)+1

// ---------------------------------------------------------------------------
// Setup: Hann window as float2 pairs + twiddle table W_2048^k, k <= 1024.
// ---------------------------------------------------------------------------
__global__ __launch_bounds__(256) void tab_kernel(
    float2* __restrict__ wtab2, float2* __restrict__ gtw) {
  int i = blockIdx.x * 256 + threadIdx.x;
  if (i < N1) {
    float w0 = 0.5f - 0.5f * cosf((float)(2.0 * M_PI / NFFT) * (float)(2 * i));
    float w1 = 0.5f - 0.5f * cosf((float)(2.0 * M_PI / NFFT) * (float)(2 * i + 1));
    wtab2[i] = make_float2(w0, w1);
  }
  if (i <= 1024) {
    float sv, cv;
    sincosf(-(float)(2.0 * M_PI / NFFT) * (float)i, &sv, &cv);
    gtw[i] = make_float2(cv, sv);
  }
}

// ---------------------------------------------------------------------------
// Kernel T: transpose fb -> fbT and exact nonzero f-range per mel filter.
// ---------------------------------------------------------------------------
__global__ __launch_bounds__(256) void fbt_kernel(
    const float* __restrict__ fb, float* __restrict__ fbT,
    int* __restrict__ fs, int* __restrict__ fe) {
  int m = blockIdx.x;
  int tid = threadIdx.x;
  __shared__ int smin[256], smax[256];
  int lmin = NFREQ, lmax = -1;
  for (int f = tid; f < NFREQ; f += 256) {
    float v = fb[f * NMELS + m];
    fbT[m * NFREQ + f] = v;
    if (v > 0.0f) {
      if (f < lmin) lmin = f;
      if (f > lmax) lmax = f;
    }
  }
  smin[tid] = lmin;
  smax[tid] = lmax;
  __syncthreads();
  for (int off = 128; off > 0; off >>= 1) {
    if (tid < off) {
      smin[tid] = min(smin[tid], smin[tid + off]);
      smax[tid] = max(smax[tid], smax[tid + off]);
    }
    __syncthreads();
  }
  if (tid == 0) {
    fs[m] = smin[0];
    fe[m] = smax[0];
  }
}

// ---------------------------------------------------------------------------
// Kernel X: transpose targets [k][m][t] -> [k][t][m] (tiled, coalesced).
// (measured round 13: tail cost ~14-17 us, enables contiguous diff chunks)
// ---------------------------------------------------------------------------
__global__ __launch_bounds__(256) void tpose_kernel(
    const float* __restrict__ tgt, float* __restrict__ tgtT) {
  __shared__ float tile[32][33];
  int k = blockIdx.z;
  int mt = blockIdx.y;            // 4 m-tiles
  int tt = blockIdx.x;            // 24 t-tiles
  int tx = threadIdx.x & 31, ty = threadIdx.x >> 5;   // 32 x 8
  const float* src = tgt + (size_t)k * MELSZ;
  float* dst = tgtT + (size_t)k * MELSZ;
  #pragma unroll
  for (int r = 0; r < 4; ++r) {
    int m = mt * 32 + ty + r * 8;
    int t = tt * 32 + tx;
    if (t < NFRAMES) tile[ty + r * 8][tx] = src[m * NFRAMES + t];
  }
  __syncthreads();
  #pragma unroll
  for (int r = 0; r < 4; ++r) {
    int t = tt * 32 + ty + r * 8;
    int m = mt * 32 + tx;
    if (t < NFRAMES) dst[t * 128 + m] = tile[tx][ty + r * 8];
  }
}

// ---------------------------------------------------------------------------
// Stockham radix-4 round, N=1024, float2-interleaved LDS (round-12 verified).
// ---------------------------------------------------------------------------
template<int L>
__device__ __forceinline__ void r4_1024(
    const float2* __restrict__ s, float2* __restrict__ d,
    const float2* __restrict__ tw, int t) {
  constexpr int LOG2L = (L == 1) ? 0 : (L == 4) ? 2 : (L == 16) ? 4
                      : (L == 64) ? 6 : 8;
  constexpr int TS = 256 / L;
  int k = t & (L - 1);
  int j = t >> LOG2L;
  int rb = SP(t);
  float2 u0 = s[rb], u1 = s[rb + 296], u2 = s[rb + 592], u3 = s[rb + 888];
  float a1r, a1i, a2r, a2i, a3r, a3i;
  if (L == 1) {
    a1r = u1.x; a1i = u1.y; a2r = u2.x; a2i = u2.y; a3r = u3.x; a3i = u3.y;
  } else {
    float2 w = tw[TP(k * TS)];
    float wc1 = w.x, ws1 = w.y;
    float wc2 = wc1 * wc1 - ws1 * ws1, ws2 = 2.0f * wc1 * ws1;
    float wc3 = wc2 * wc1 - ws2 * ws1, ws3 = wc2 * ws1 + ws2 * wc1;
    a1r = wc1 * u1.x - ws1 * u1.y; a1i = wc1 * u1.y + ws1 * u1.x;
    a2r = wc2 * u2.x - ws2 * u2.y; a2i = wc2 * u2.y + ws2 * u2.x;
    a3r = wc3 * u3.x - ws3 * u3.y; a3i = wc3 * u3.y + ws3 * u3.x;
  }
  float s0r = u0.x + a2r, s0i = u0.y + a2i;
  float d0r = u0.x - a2r, d0i = u0.y - a2i;
  float s1r = a1r + a3r, s1i = a1i + a3i;
  float d1r = a1r - a3r, d1i = a1i - a3i;
  int wb = (j << (LOG2L + 2)) + k;
  d[SP(wb)]         = make_float2(s0r + s1r, s0i + s1i);
  d[SP(wb + L)]     = make_float2(d0r + d1i, d0i - d1r);
  d[SP(wb + 2 * L)] = make_float2(s0r - s1r, s0i - s1i);
  d[SP(wb + 3 * L)] = make_float2(d0r - d1i, d0i + d1r);
}

// ---------------------------------------------------------------------------
// Kernel A (round-12 structure, 153 us measured, + coalesced [b][t][m] write):
// one block per (batch, frame); even/odd-packed 1024-pt Stockham FFT;
// 20.9 KB LDS -> 7 blocks/CU; unpack to powers; sparse mel; 512 B write.
// ---------------------------------------------------------------------------
__global__ __launch_bounds__(256) void melspec_kernel(
    const float* __restrict__ x, const float* __restrict__ fbT,
    const int* __restrict__ fs, const int* __restrict__ fe,
    const float2* __restrict__ wtab2, const float2* __restrict__ gtw,
    float* __restrict__ mel) {
  __shared__ float2 zA[SBUF1];
  __shared__ float2 zB[SBUF1];
  __shared__ float2 twl[TWP];   // total 20968 B

  int tid = threadIdx.x;
  int b = blockIdx.x / NFRAMES;
  int t = blockIdx.x - b * NFRAMES;
  const float* xb = x + (size_t)b * SRATE;

  // stage W_1024 round twiddles: W_1024^j = W_2048^{2j}
  twl[TP(tid)] = gtw[2 * tid];

  // load frame: z[n] = xw[2n] + i*xw[2n+1]; float2 global loads on the
  // common non-reflected path.
  int base = t * HOP - NFFT / 2;
  for (int n = tid; n < N1; n += 256) {
    int p0 = base + 2 * n;
    float2 v;
    if (p0 >= 0 && p0 + 1 < SRATE) {
      v = *(const float2*)(xb + p0);
    } else {
      int q0 = p0 < 0 ? -p0 : (p0 >= SRATE ? 2 * SRATE - 2 - p0 : p0);
      int p1 = p0 + 1;
      int q1 = p1 < 0 ? -p1 : (p1 >= SRATE ? 2 * SRATE - 2 - p1 : p1);
      v = make_float2(xb[q0], xb[q1]);
    }
    float2 w2 = wtab2[n];
    zA[SP(n)] = make_float2(v.x * w2.x, v.y * w2.y);
  }
  __syncthreads();

  r4_1024<1>(zA, zB, twl, tid);   __syncthreads();
  r4_1024<4>(zB, zA, twl, tid);   __syncthreads();
  r4_1024<16>(zA, zB, twl, tid);  __syncthreads();
  r4_1024<64>(zB, zA, twl, tid);  __syncthreads();
  r4_1024<256>(zA, zB, twl, tid); __syncthreads();
  // natural-order Z in zB; zA free -> plain-indexed power array

  float* pw = (float*)zA;
  for (int k = tid; k <= 1024; k += 256) {
    int ka = SP(k & (N1 - 1)), kb = SP((N1 - k) & (N1 - 1));
    float2 Za = zB[ka], Zb = zB[kb];
    float Xer  = 0.5f * (Za.x + Zb.x), Xei = 0.5f * (Za.y - Zb.y);
    float Xor_ = 0.5f * (Za.y + Zb.y), Xoi = 0.5f * (Zb.x - Za.x);
    float2 w = gtw[k];
    float Xr = Xer + w.x * Xor_ - w.y * Xoi;
    float Xi = Xei + w.x * Xoi + w.y * Xor_;
    pw[k] = Xr * Xr + Xi * Xi;
  }
  __syncthreads();

  // sparse mel projection: 2 threads per filter; coalesced [b][t][m] write
  int m = tid >> 1, half = tid & 1;
  int f0 = fs[m], f1 = fe[m];
  int mid = f0 + ((f1 - f0 + 1) >> 1);
  int lo = half ? mid : f0;
  int hi = half ? f1 : mid - 1;
  const float* col = fbT + (size_t)m * NFREQ;
  float acc = 0.0f;
  for (int f = lo; f <= hi; ++f) acc += pw[f] * col[f];
  acc += __shfl_xor(acc, 1);
  if (!half) mel[(size_t)b * MELSZ + (size_t)t * 128 + m] = acc;
}

// ---------------------------------------------------------------------------
// Kernel B: L1 partials; chunk c = frame t (128 contiguous floats in both
// mel [b][t][m] and tgtT [k][t][m]); atomicAdd into diffs[2048].
// ---------------------------------------------------------------------------
__global__ __launch_bounds__(256) void diff_kernel(
    const float* __restrict__ mel, const float* __restrict__ tgtT,
    float* __restrict__ diffs) {
  __shared__ float mel_s[BATCH * PADW];
  __shared__ float tgt_s[NTGT * PADW];
  int tid = threadIdx.x;
  int bg = tid >> 4;        // 0..15 -> b in {2bg, 2bg+1}
  int kg = tid & 15;        // 0..15 -> k in {kg + 16i}, i<4
  int c = blockIdx.x;

  for (int q = tid; q < BATCH * 32; q += 256) {
    int row = q >> 5, c4 = q & 31;
    float4 v = *(const float4*)(mel + (size_t)row * MELSZ + c * 128 + c4 * 4);
    *(float4*)(&mel_s[row * PADW + c4 * 4]) = v;
  }
  for (int q = tid; q < NTGT * 32; q += 256) {
    int row = q >> 5, c4 = q & 31;
    float4 v = *(const float4*)(tgtT + (size_t)row * MELSZ + c * 128 + c4 * 4);
    *(float4*)(&tgt_s[row * PADW + c4 * 4]) = v;
  }
  __syncthreads();

  float acc[2][4];
  #pragma unroll
  for (int bi = 0; bi < 2; ++bi)
    #pragma unroll
    for (int i = 0; i < 4; ++i) acc[bi][i] = 0.0f;

  for (int j4 = 0; j4 < 32; ++j4) {
    float4 m0 = *(const float4*)(&mel_s[(2 * bg) * PADW + j4 * 4]);
    float4 m1 = *(const float4*)(&mel_s[(2 * bg + 1) * PADW + j4 * 4]);
    #pragma unroll
    for (int i = 0; i < 4; ++i) {
      int k = kg + (i << 4);
      float4 tv = *(const float4*)(&tgt_s[k * PADW + j4 * 4]);
      acc[0][i] += fabsf(m0.x - tv.x) + fabsf(m0.y - tv.y) +
                   fabsf(m0.z - tv.z) + fabsf(m0.w - tv.w);
      acc[1][i] += fabsf(m1.x - tv.x) + fabsf(m1.y - tv.y) +
                   fabsf(m1.z - tv.z) + fabsf(m1.w - tv.w);
    }
  }

  #pragma unroll
  for (int bi = 0; bi < 2; ++bi)
    #pragma unroll
    for (int i = 0; i < 4; ++i)
      atomicAdd(&diffs[(2 * bg + bi) * 64 + kg + (i << 4)], acc[bi][i]);
}

// ---------------------------------------------------------------------------
// Kernel C: scale by 1/MELSZ, min over 64 targets per batch row.
// ---------------------------------------------------------------------------
__global__ __launch_bounds__(256) void reduce_kernel(
    const float* __restrict__ diffs, float* __restrict__ out) {
  __shared__ float ds[256];
  int tid = threadIdx.x;
  int p = blockIdx.x * 256 + tid;
  ds[tid] = diffs[p] * (1.0f / (float)MELSZ);
  __syncthreads();
  if (tid < 4) {
    float mn = ds[tid * 64];
    #pragma unroll
    for (int kk = 1; kk < 64; ++kk) mn = fminf(mn, ds[tid * 64 + kk]);
    out[blockIdx.x * 4 + tid] = mn;
  }
}

// ---------------------------------------------------------------------------
extern "C" void kernel_launch(void* const* d_in, const int* in_sizes, int n_in,
                              void* d_out, int out_size, void* d_ws, size_t ws_size,
                              hipStream_t stream) {
  const float* x   = (const float*)d_in[0];   // (32, 48000)
  const float* tgt = (const float*)d_in[1];   // (64, 128, 751)
  const float* fb  = (const float*)d_in[2];   // (1025, 128)
  float* out = (float*)d_out;                 // (32,)

  char* ws = (char*)d_ws;
  size_t off = 0;
  float* fbT = (float*)(ws + off);
  off += ((size_t)NMELS * NFREQ * sizeof(float) + 255) & ~(size_t)255;
  int* fs = (int*)(ws + off); off += 1024;
  int* fe = (int*)(ws + off); off += 1024;
  float2* wtab2 = (float2*)(ws + off); off += N1 * sizeof(float2);
  float2* gtw   = (float2*)(ws + off); off += 1056 * sizeof(float2);
  float* mel = (float*)(ws + off);
  off += (size_t)BATCH * MELSZ * sizeof(float);
  float* tgtT = (float*)(ws + off);
  off += (size_t)NTGT * MELSZ * sizeof(float);
  float* diffs = (float*)(ws + off); off += 2048 * sizeof(float);

  hipMemsetAsync(diffs, 0, 2048 * sizeof(float), stream);
  tab_kernel<<<8, 256, 0, stream>>>(wtab2, gtw);
  fbt_kernel<<<NMELS, 256, 0, stream>>>(fb, fbT, fs, fe);
  tpose_kernel<<<dim3(24, 4, NTGT), 256, 0, stream>>>(tgt, tgtT);
  melspec_kernel<<<BATCH * NFRAMES, 256, 0, stream>>>(
      x, fbT, fs, fe, wtab2, gtw, mel);
  diff_kernel<<<NCHUNK, 256, 0, stream>>>(mel, tgtT, diffs);
  reduce_kernel<<<8, 256, 0, stream>>>(diffs, out);
}